// Round 2
// baseline (13710.083 us; speedup 1.0000x reference)
//
#include <hip/hip_runtime.h>

// LSTM net: linear1(20->50) -> 3x LSTMCell(50, buggy c-flow) -> linear2(50->8)
// B=512, T=1024.  256 blocks x 768 threads (12 waves), 2 batch elems/block.
//
// R1 redesign: h-import via ONE ds_read_b128 per wave (lanes 0-49 hold the
// 200 floats of {vA|vB}) + v_readlane broadcast -> SGPR operand in packed
// FMAs.  Kills the ~5600 cyc/step of broadcast ds_read_b128 traffic seen in
// R0 (LDS-issue bound, 12 cyc/instr even for uniform addresses).
//
// Wave layout: wave w = layer l (w>>2), gate-type g (w&3); lanes 0-49 = units.
//   waves 0-7  lanes 50-63 : linear1 prefetch (100 lanes, t = s+2)
//   waves 8,9  lanes 50-57 : out-projection, piggybacks the h3 readlane stream
// Pipeline skew (as R0): L1 t=s, L2 t=s-1, L3 t=s-2, out t=s-3.

#define T_SEQ  1024
#define IN_DIM 20
#define OUT_DIM 8

typedef float f2 __attribute__((ext_vector_type(2)));

__device__ __forceinline__ float rl(float v, int lane) {
    return __int_as_float(__builtin_amdgcn_readlane(__float_as_int(v), lane));
}
__device__ __forceinline__ float sigm(float x) {
    return __builtin_amdgcn_rcpf(1.0f + __expf(-x));
}
__device__ __forceinline__ float tanh_f(float x) {
    return fmaf(2.0f, sigm(2.0f * x), -1.0f);
}
__device__ __forceinline__ f2 fma2(float w, f2 h, f2 acc) {
    return __builtin_elementwise_fma((f2){w, w}, h, acc);
}

__global__ __launch_bounds__(768, 3) void lstm_net_kernel(
    const float* __restrict__ x,
    const float* __restrict__ W1,   const float* __restrict__ b1,
    const float* __restrict__ Wih1, const float* __restrict__ Whh1,
    const float* __restrict__ bih1, const float* __restrict__ bhh1,
    const float* __restrict__ Wih2, const float* __restrict__ Whh2,
    const float* __restrict__ bih2, const float* __restrict__ bhh2,
    const float* __restrict__ Wih3, const float* __restrict__ Whh3,
    const float* __restrict__ bih3, const float* __restrict__ bhh3,
    const float* __restrict__ W2,   const float* __restrict__ b2,
    float* __restrict__ out)
{
    __shared__ __align__(16) f2 smem[1050];
    f2* xbuf  = smem;        // [3][50] ring by s%3
    f2* h1buf = smem + 150;  // [2][50]
    f2* h2buf = smem + 250;  // [2][50]
    f2* h3buf = smem + 350;  // [2][50]
    f2* gbuf  = smem + 450;  // [(l*4+g)*50 + j], 600 f2

    const int tid  = threadIdx.x;
    const int w    = tid >> 6;
    const int lane = tid & 63;
    const int l    = w >> 2;
    const int g    = w & 3;
    const int b0   = blockIdx.x * 2;
    const bool outW = (w == 8) || (w == 9);

    for (int i = tid; i < 1050; i += 768) smem[i] = (f2){0.f, 0.f};

    // ---- role init (once) ----
    float wA[50], wB[50];
    float bias = 0.f;
    float ga = 1.f, gc = 0.f;            // activation: ga*sigm(ga*x)+gc
    int   pb = 0, pj = 0;
    bool  preLane = false;
    f2    c1 = {0.f, 0.f};               // L1 cell (wave 0 lanes 0-49)

    if (lane < 50) {
        const float* Wih = (l == 0) ? Wih1 : (l == 1 ? Wih2 : Wih3);
        const float* Whh = (l == 0) ? Whh1 : (l == 1 ? Whh2 : Whh3);
        const float* bi  = (l == 0) ? bih1 : (l == 1 ? bih2 : bih3);
        const float* bh  = (l == 0) ? bhh1 : (l == 1 ? bhh2 : bhh3);
        const int row = g * 50 + lane;
        #pragma unroll
        for (int k = 0; k < 50; ++k) { wA[k] = Wih[row * 50 + k]; }
        #pragma unroll
        for (int k = 0; k < 50; ++k) { wB[k] = Whh[row * 50 + k]; }
        bias = bi[row] + bh[row];
        if (g == 2) { ga = 2.f; gc = -1.f; }   // tanh gate
    } else if (outW && lane < 58) {
        const int od = lane - 50;
        #pragma unroll
        for (int k = 0; k < 50; ++k) { wA[k] = 0.f; wB[k] = W2[od * 50 + k]; }
        bias = b2[od];
    } else if (w < 8) {
        const int idx = w * 14 + (lane - 50);
        if (idx < 100) {
            preLane = true; pb = idx / 50; pj = idx % 50;
            #pragma unroll
            for (int k = 0; k < 20; ++k) wA[k] = W1[pj * 20 + k];
            bias = b1[pj];
        }
    }
    __syncthreads();

    // prologue: x~(0), x~(1) into xbuf slots 0,1
    if (preLane) {
        #pragma unroll
        for (int t0 = 0; t0 < 2; ++t0) {
            const float* xp = x + ((size_t)(b0 + pb) * T_SEQ + t0) * IN_DIM;
            float v = bias;
            #pragma unroll
            for (int k = 0; k < 20; ++k) v = fmaf(wA[k], xp[k], v);
            ((float*)(xbuf + t0 * 50 + pj))[pb] = v;
        }
    }
    __syncthreads();

    for (int s = 0; s < T_SEQ + 3; ++s) {
        const int p = s & 1, pm = p ^ 1, q3 = s % 3;

        // ======== phase A: gates (+out piggyback) ========
        bool run;
        if (outW) run = (s >= 2) && (s <= T_SEQ + 2);
        else      run = (s >= l) && (s < T_SEQ + l);

        if (run && (lane < 50 || outW)) {
            const f2* vA; const f2* vB;
            if (l == 0)      { vA = xbuf  + q3 * 50; vB = h1buf + pm * 50; }
            else if (l == 1) { vA = h1buf + pm * 50; vB = h2buf + p  * 50; }
            else             { vA = h2buf + p  * 50; vB = h3buf + pm * 50; }

            // one ds_read_b128: lanes 0-24 hold vA, lanes 25-49 hold vB
            const f2* srcp = (lane < 25) ? (vA + 2 * lane)
                          : (lane < 50) ? (vB + 2 * (lane - 25)) : vA;
            float4 my = *(const float4*)srcp;

            f2 accA  = {bias, bias}, accA1 = {0.f, 0.f};
            f2 accB  = {0.f, 0.f},   accB1 = {0.f, 0.f};
            #pragma unroll
            for (int c = 0; c < 25; ++c) {
                f2 h0  = {rl(my.x, c), rl(my.y, c)};
                f2 h1v = {rl(my.z, c), rl(my.w, c)};
                accA  = fma2(wA[2 * c],     h0,  accA);
                accA1 = fma2(wA[2 * c + 1], h1v, accA1);
            }
            #pragma unroll
            for (int c = 0; c < 25; ++c) {
                f2 h0  = {rl(my.x, 25 + c), rl(my.y, 25 + c)};
                f2 h1v = {rl(my.z, 25 + c), rl(my.w, 25 + c)};
                accB  = fma2(wB[2 * c],     h0,  accB);
                accB1 = fma2(wB[2 * c + 1], h1v, accB1);
            }
            f2 pa = (accA + accA1) + (accB + accB1);

            if (lane < 50) {
                if (s - l < T_SEQ) {
                    f2 r;
                    r.x = fmaf(ga, sigm(ga * pa.x), gc);
                    r.y = fmaf(ga, sigm(ga * pa.y), gc);
                    gbuf[(l * 4 + g) * 50 + lane] = r;
                }
            } else if (s >= 3 && lane < 58) {
                const int t = s - 3;
                const float res = (w == 8) ? pa.x : pa.y;
                out[((size_t)(b0 + (w - 8)) * T_SEQ + t) * OUT_DIM + (lane - 50)] = res;
            }
        }

        // linear1 prefetch for t = s+2
        if (preLane && s + 2 < T_SEQ) {
            const int t = s + 2;
            const float* xp = x + ((size_t)(b0 + pb) * T_SEQ + t) * IN_DIM;
            float v = bias;
            #pragma unroll
            for (int k = 0; k < 20; ++k) v = fmaf(wA[k], xp[k], v);
            ((float*)(xbuf + (t % 3) * 50 + pj))[pb] = v;
        }
        __syncthreads();

        // ======== phase B: combines ========
        if (w == 0 && lane < 50 && s < T_SEQ) {          // L1, t = s
            f2 gi = gbuf[lane],       gf = gbuf[50 + lane];
            f2 gg = gbuf[100 + lane], go = gbuf[150 + lane];
            c1 = __builtin_elementwise_fma(gf, c1, gi * gg);
            f2 h;
            h.x = go.x * tanh_f(c1.x);
            h.y = go.y * tanh_f(c1.y);
            h1buf[p * 50 + lane] = h;
        }
        if (w == 4 && lane < 50) {
            f2 cn3 = {0.f, 0.f};
            if (s >= 2 && s <= T_SEQ + 1) {              // L3, t3 = s-2 (c3==0)
                f2 gi = gbuf[400 + lane], gg = gbuf[500 + lane], go = gbuf[550 + lane];
                cn3 = gi * gg;
                f2 h;
                h.x = go.x * tanh_f(cn3.x);
                h.y = go.y * tanh_f(cn3.y);
                h3buf[p * 50 + lane] = h;
            }
            if (s >= 1 && s <= T_SEQ) {                  // L2, t2 = s-1 (c2 <- cn3)
                f2 gi = gbuf[200 + lane], gf = gbuf[250 + lane];
                f2 gg = gbuf[300 + lane], go = gbuf[350 + lane];
                f2 c2n = __builtin_elementwise_fma(gf, cn3, gi * gg);
                f2 h;
                h.x = go.x * tanh_f(c2n.x);
                h.y = go.y * tanh_f(c2n.y);
                h2buf[pm * 50 + lane] = h;
            }
        }
        __syncthreads();
    }
}

extern "C" void kernel_launch(void* const* d_in, const int* in_sizes, int n_in,
                              void* d_out, int out_size, void* d_ws, size_t ws_size,
                              hipStream_t stream) {
    const float* x    = (const float*)d_in[0];
    const float* W1   = (const float*)d_in[1];
    const float* b1   = (const float*)d_in[2];
    const float* Wih1 = (const float*)d_in[3];
    const float* Whh1 = (const float*)d_in[4];
    const float* bih1 = (const float*)d_in[5];
    const float* bhh1 = (const float*)d_in[6];
    const float* Wih2 = (const float*)d_in[7];
    const float* Whh2 = (const float*)d_in[8];
    const float* bih2 = (const float*)d_in[9];
    const float* bhh2 = (const float*)d_in[10];
    const float* Wih3 = (const float*)d_in[11];
    const float* Whh3 = (const float*)d_in[12];
    const float* bih3 = (const float*)d_in[13];
    const float* bhh3 = (const float*)d_in[14];
    const float* W2   = (const float*)d_in[15];
    const float* b2   = (const float*)d_in[16];
    float* out = (float*)d_out;

    dim3 grid(256), block(768);
    lstm_net_kernel<<<grid, block, 0, stream>>>(
        x, W1, b1, Wih1, Whh1, bih1, bhh1, Wih2, Whh2, bih2, bhh2,
        Wih3, Whh3, bih3, bhh3, W2, b2, out);
}

// Round 4
// 3540.115 us; speedup vs baseline: 3.8728x; 3.8728x over previous
//
#include <hip/hip_runtime.h>

// LSTM net: linear1(20->50) -> 3x LSTMCell(50, buggy c-flow) -> linear2(50->8)
// B=512, T=1024.  256 blocks x 768 threads (12 waves), 2 batch elems/block.
//
// R4 = R3 with the OOB fix: outW must be waves 8,9 ONLY (w>=8 also caught
// waves 10,11 -> they stored out for batches b0+2/b0+3 -> OOB on block 255).
//
// Design: readlane-broadcast h-import.
//   - ONE ds_read_b128 per gate wave per step: lanes 0-24 hold vA (input
//     h-vector), lanes 25-49 hold vB (recurrent h-vector), 4 floats each.
//   - Broadcast via v_readlane -> SGPR, consumed as the scalar operand of
//     plain v_fma_f32 (no f2 temporaries -- R2's {rl,rl} pairs caused v_mov
//     pressure -> weight arrays spilled to scratch -> 27 GB HBM traffic).
// Wave layout: wave w = layer (w>>2), gate-type (w&3); lanes 0-49 = units.
//   waves 0-7 lanes 50-63: linear1 prefetch (t = s+2).
//   waves 8,9 lanes 50-57: out-projection piggybacks L3's readlane stream.
// Pipeline skew: L1 t=s, L2 t=s-1, L3 t=s-2, out t=s-3 (bug: c2 <- L3 cell).

#define T_SEQ  1024
#define IN_DIM 20
#define OUT_DIM 8

typedef float f2 __attribute__((ext_vector_type(2)));

__device__ __forceinline__ float rl(float v, int lane) {
    return __int_as_float(__builtin_amdgcn_readlane(__float_as_int(v), lane));
}
__device__ __forceinline__ float sigm(float x) {
    return __builtin_amdgcn_rcpf(1.0f + __expf(-x));
}
__device__ __forceinline__ float tanh_f(float x) {
    return fmaf(2.0f, sigm(2.0f * x), -1.0f);
}

__global__ __launch_bounds__(768, 3) void lstm_net_kernel(
    const float* __restrict__ x,
    const float* __restrict__ W1,   const float* __restrict__ b1,
    const float* __restrict__ Wih1, const float* __restrict__ Whh1,
    const float* __restrict__ bih1, const float* __restrict__ bhh1,
    const float* __restrict__ Wih2, const float* __restrict__ Whh2,
    const float* __restrict__ bih2, const float* __restrict__ bhh2,
    const float* __restrict__ Wih3, const float* __restrict__ Whh3,
    const float* __restrict__ bih3, const float* __restrict__ bhh3,
    const float* __restrict__ W2,   const float* __restrict__ b2,
    float* __restrict__ out)
{
    __shared__ __align__(16) f2 smem[1050];
    f2* xbuf  = smem;        // [3][50] ring by t%3
    f2* h1buf = smem + 150;  // [2][50]
    f2* h2buf = smem + 250;  // [2][50]
    f2* h3buf = smem + 350;  // [2][50]
    f2* gbuf  = smem + 450;  // [(l*4+g)*50 + j]

    const int tid  = threadIdx.x;
    const int w    = tid >> 6;
    const int lane = tid & 63;
    const int l    = w >> 2;
    const int g    = w & 3;
    const int b0   = blockIdx.x * 2;
    const bool outW = (w == 8) || (w == 9);   // ONLY 8,9 (w>=8 was the R3 bug)

    for (int i = tid; i < 1050; i += 768) smem[i] = (f2){0.f, 0.f};

    // ---- role init ----
    float wA[50], wB[50];
    float bias = 0.f;
    float ga = 1.f, gc = 0.f;            // activation: ga*sigm(ga*x)+gc
    int   pb = 0, pj = 0;
    bool  preLane = false;
    f2    c1 = {0.f, 0.f};

    if (lane < 50) {
        const float* Wih = (l == 0) ? Wih1 : (l == 1 ? Wih2 : Wih3);
        const float* Whh = (l == 0) ? Whh1 : (l == 1 ? Whh2 : Whh3);
        const float* bi  = (l == 0) ? bih1 : (l == 1 ? bih2 : bih3);
        const float* bh  = (l == 0) ? bhh1 : (l == 1 ? bhh2 : bhh3);
        const int row = g * 50 + lane;
        #pragma unroll
        for (int k = 0; k < 50; ++k) wA[k] = Wih[row * 50 + k];
        #pragma unroll
        for (int k = 0; k < 50; ++k) wB[k] = Whh[row * 50 + k];
        bias = bi[row] + bh[row];
        if (g == 2) { ga = 2.f; gc = -1.f; }          // tanh gate
    } else if (outW && lane < 58) {
        const int od = lane - 50;
        #pragma unroll
        for (int k = 0; k < 50; ++k) { wA[k] = 0.f; wB[k] = W2[od * 50 + k]; }
        bias = b2[od];
    } else if (w < 8) {
        const int idx = w * 14 + (lane - 50);
        if (idx < 100) {
            preLane = true; pb = idx / 50; pj = idx % 50;
            #pragma unroll
            for (int k = 0; k < 20; ++k) wA[k] = W1[pj * 20 + k];
            bias = b1[pj];
        }
    }
    __syncthreads();

    if (preLane) {                        // prologue: x~(0), x~(1)
        #pragma unroll
        for (int t0 = 0; t0 < 2; ++t0) {
            const float* xp = x + ((size_t)(b0 + pb) * T_SEQ + t0) * IN_DIM;
            float v = bias;
            #pragma unroll
            for (int k = 0; k < 20; ++k) v = fmaf(wA[k], xp[k], v);
            ((float*)(xbuf + t0 * 50 + pj))[pb] = v;
        }
    }
    __syncthreads();

    for (int s = 0; s < T_SEQ + 3; ++s) {
        const int p = s & 1, pm = p ^ 1, q3 = s % 3;

        // ======== phase A: gate dots (+out piggyback) ========
        bool run;
        if (outW) run = (s >= 2) && (s <= T_SEQ + 2);
        else      run = (s >= l) && (s < T_SEQ + l);

        if (run && (lane < 50 || outW)) {
            const f2* vA; const f2* vB;
            if (l == 0)      { vA = xbuf  + q3 * 50; vB = h1buf + pm * 50; }
            else if (l == 1) { vA = h1buf + pm * 50; vB = h2buf + p  * 50; }
            else             { vA = h2buf + p  * 50; vB = h3buf + pm * 50; }

            const f2* srcp = (lane < 25) ? (vA + 2 * lane)
                          : (lane < 50) ? (vB + 2 * (lane - 25)) : vA;
            float4 my = *(const float4*)srcp;         // one ds_read_b128

            float ax = bias, ay = bias, bx = 0.f, by = 0.f;
            #pragma unroll
            for (int c = 0; c < 25; ++c) {            // A-half (lanes 0-24)
                float w0 = wA[2 * c], w1 = wA[2 * c + 1];
                ax = fmaf(w0, rl(my.x, c), ax);
                ay = fmaf(w0, rl(my.y, c), ay);
                bx = fmaf(w1, rl(my.z, c), bx);
                by = fmaf(w1, rl(my.w, c), by);
            }
            #pragma unroll
            for (int c = 0; c < 25; ++c) {            // B-half (lanes 25-49)
                float w0 = wB[2 * c], w1 = wB[2 * c + 1];
                ax = fmaf(w0, rl(my.x, 25 + c), ax);
                ay = fmaf(w0, rl(my.y, 25 + c), ay);
                bx = fmaf(w1, rl(my.z, 25 + c), bx);
                by = fmaf(w1, rl(my.w, 25 + c), by);
            }
            float px_ = ax + bx, py_ = ay + by;

            if (lane < 50) {
                if (s - l < T_SEQ) {
                    f2 r;
                    r.x = fmaf(ga, sigm(ga * px_), gc);
                    r.y = fmaf(ga, sigm(ga * py_), gc);
                    gbuf[(l * 4 + g) * 50 + lane] = r;
                }
            } else if (s >= 3 && lane < 58) {
                const int t = s - 3;
                const float res = (w == 8) ? px_ : py_;
                out[((size_t)(b0 + (w - 8)) * T_SEQ + t) * OUT_DIM + (lane - 50)] = res;
            }
        }

        if (preLane && s + 2 < T_SEQ) {               // linear1, t = s+2
            const int t = s + 2;
            const float* xp = x + ((size_t)(b0 + pb) * T_SEQ + t) * IN_DIM;
            float v = bias;
            #pragma unroll
            for (int k = 0; k < 20; ++k) v = fmaf(wA[k], xp[k], v);
            ((float*)(xbuf + (t % 3) * 50 + pj))[pb] = v;
        }
        __syncthreads();

        // ======== phase B: combines ========
        if (w == 0 && lane < 50 && s < T_SEQ) {       // L1, t = s
            f2 gi = gbuf[lane],       gf = gbuf[50 + lane];
            f2 gg = gbuf[100 + lane], go = gbuf[150 + lane];
            c1 = __builtin_elementwise_fma(gf, c1, gi * gg);
            f2 h;
            h.x = go.x * tanh_f(c1.x);
            h.y = go.y * tanh_f(c1.y);
            h1buf[p * 50 + lane] = h;
        }
        if (w == 4 && lane < 50) {
            f2 cn3 = {0.f, 0.f};
            if (s >= 2 && s <= T_SEQ + 1) {           // L3, t3 = s-2 (c3==0)
                f2 gi = gbuf[400 + lane], gg = gbuf[500 + lane], go = gbuf[550 + lane];
                cn3 = gi * gg;
                f2 h;
                h.x = go.x * tanh_f(cn3.x);
                h.y = go.y * tanh_f(cn3.y);
                h3buf[p * 50 + lane] = h;
            }
            if (s >= 1 && s <= T_SEQ) {               // L2, t2 = s-1 (c2 <- cn3)
                f2 gi = gbuf[200 + lane], gf = gbuf[250 + lane];
                f2 gg = gbuf[300 + lane], go = gbuf[350 + lane];
                f2 c2n = __builtin_elementwise_fma(gf, cn3, gi * gg);
                f2 h;
                h.x = go.x * tanh_f(c2n.x);
                h.y = go.y * tanh_f(c2n.y);
                h2buf[pm * 50 + lane] = h;
            }
        }
        __syncthreads();
    }
}

extern "C" void kernel_launch(void* const* d_in, const int* in_sizes, int n_in,
                              void* d_out, int out_size, void* d_ws, size_t ws_size,
                              hipStream_t stream) {
    const float* x    = (const float*)d_in[0];
    const float* W1   = (const float*)d_in[1];
    const float* b1   = (const float*)d_in[2];
    const float* Wih1 = (const float*)d_in[3];
    const float* Whh1 = (const float*)d_in[4];
    const float* bih1 = (const float*)d_in[5];
    const float* bhh1 = (const float*)d_in[6];
    const float* Wih2 = (const float*)d_in[7];
    const float* Whh2 = (const float*)d_in[8];
    const float* bih2 = (const float*)d_in[9];
    const float* bhh2 = (const float*)d_in[10];
    const float* Wih3 = (const float*)d_in[11];
    const float* Whh3 = (const float*)d_in[12];
    const float* bih3 = (const float*)d_in[13];
    const float* bhh3 = (const float*)d_in[14];
    const float* W2   = (const float*)d_in[15];
    const float* b2   = (const float*)d_in[16];
    float* out = (float*)d_out;

    dim3 grid(256), block(768);
    lstm_net_kernel<<<grid, block, 0, stream>>>(
        x, W1, b1, Wih1, Whh1, bih1, bhh1, Wih2, Whh2, bih2, bhh2,
        Wih3, Whh3, bih3, bhh3, W2, b2, out);
}

// Round 5
// 2658.420 us; speedup vs baseline: 5.1572x; 1.3317x over previous
//
#include <hip/hip_runtime.h>

// LSTM net: linear1(20->50) -> 3x LSTMCell(50, buggy c-flow) -> linear2(50->8)
// B=512, T=1024.  256 blocks x 512 threads (8 waves), 2 batch elems/block.
//
// R5: cut the DS-broadcast bottleneck (R0: ~500 uniform ds_read_b128/step/CU
// = ~5240 cyc) by (a) merging 4 gates into one lane (lane = unit's i,f,g,o;
// combine is IN-LANE, gbuf eliminated) and (b) lane-pair K-split (even lane:
// Wih*vA half, odd lane: Whh*vB half; merge via ds_swizzle xor-1 butterfly).
// DS drops to 6 waves x 25 b128 = 150 broadcasts/step (~1800 cyc).
// Weights: 4 gates x 50 K = 200 VGPR/lane, within 256-reg @ 2 waves/SIMD.
//
// Wave roles: w=0..5 gates (layer=w>>1, unit-half=w&1; lane: u=(w&1)*25+lane/2,
// kside=lane&1); w=6 linear1 prefetch (t=s+2, ring-3 xbuf); w=7 out-proj
// (t=s-3, 8 lanes).  Pipeline skew: L1 t=s, L2 t=s-1, L3 t=s-2, out t=s-3.
// Bug flow: c2 <- L3 cell (cn3buf, same-step phase-B), c3 stays 0.

#define T_SEQ  1024
#define IN_DIM 20
#define OUT_DIM 8

typedef float f2 __attribute__((ext_vector_type(2)));

__device__ __forceinline__ float swz1(float v) {   // lane ^= 1 butterfly
    return __int_as_float(__builtin_amdgcn_ds_swizzle(__float_as_int(v), 0x041F));
}
__device__ __forceinline__ float sigm(float x) {
    return __builtin_amdgcn_rcpf(1.0f + __expf(-x));
}
__device__ __forceinline__ float tanh_f(float x) {
    return fmaf(2.0f, sigm(2.0f * x), -1.0f);
}

__global__ __launch_bounds__(512, 2) void lstm_net_kernel(
    const float* __restrict__ x,
    const float* __restrict__ W1,   const float* __restrict__ b1,
    const float* __restrict__ Wih1, const float* __restrict__ Whh1,
    const float* __restrict__ bih1, const float* __restrict__ bhh1,
    const float* __restrict__ Wih2, const float* __restrict__ Whh2,
    const float* __restrict__ bih2, const float* __restrict__ bhh2,
    const float* __restrict__ Wih3, const float* __restrict__ Whh3,
    const float* __restrict__ bih3, const float* __restrict__ bhh3,
    const float* __restrict__ W2,   const float* __restrict__ b2,
    float* __restrict__ out)
{
    __shared__ __align__(16) f2 smem[500];
    f2* xbuf   = smem;         // [3][50] ring by t%3
    f2* h1buf  = smem + 150;   // [2][50]
    f2* h2buf  = smem + 250;   // [2][50]
    f2* h3buf  = smem + 350;   // [2][50]
    f2* cn3buf = smem + 450;   // [50], single-buffered (A-write, B-read)

    const int tid  = threadIdx.x;
    const int w    = tid >> 6;
    const int lane = tid & 63;
    const int b0   = blockIdx.x * 2;

    for (int i = tid; i < 500; i += 512) smem[i] = (f2){0.f, 0.f};

    const int l     = w >> 1;              // gate-wave layer
    const int kside = lane & 1;            // 0: Wih*vA half, 1: Whh*vB half
    const int u     = (w & 1) * 25 + (lane >> 1);   // unit index

    float wt[200];                          // shared across roles (R0 trick)
    float bs0 = 0.f, bs1 = 0.f, bs2 = 0.f, bs3 = 0.f;
    float c1x = 0.f, c1y = 0.f;             // L1 cell (valid on l==0 lanes)
    float sg[8];                            // saved activated L2 gates

    if (w < 6) {
        if (lane < 50) {
            const float* Wsrc; const float* bi; const float* bh;
            if (l == 0)      { Wsrc = kside ? Whh1 : Wih1; bi = bih1; bh = bhh1; }
            else if (l == 1) { Wsrc = kside ? Whh2 : Wih2; bi = bih2; bh = bhh2; }
            else             { Wsrc = kside ? Whh3 : Wih3; bi = bih3; bh = bhh3; }
            #pragma unroll
            for (int g = 0; g < 4; ++g)
                #pragma unroll
                for (int k = 0; k < 50; ++k)
                    wt[g * 50 + k] = Wsrc[(g * 50 + u) * 50 + k];
            if (!kside) {                   // bias only on the A-side lane
                bs0 = bi[u]       + bh[u];
                bs1 = bi[50 + u]  + bh[50 + u];
                bs2 = bi[100 + u] + bh[100 + u];
                bs3 = bi[150 + u] + bh[150 + u];
            }
        }
    } else if (w == 6) {
        if (lane < 50) {
            #pragma unroll
            for (int k = 0; k < 20; ++k) wt[k] = W1[lane * 20 + k];
            bs0 = b1[lane];
        }
    } else {
        if (lane < 8) {
            #pragma unroll
            for (int k = 0; k < 50; ++k) wt[k] = W2[lane * 50 + k];
            bs0 = b2[lane];
        }
    }
    __syncthreads();

    if (w == 6 && lane < 50) {              // prologue: x~(0), x~(1)
        for (int t0 = 0; t0 < 2; ++t0) {
            const float* xp0 = x + ((size_t)b0 * T_SEQ + t0) * IN_DIM;
            const float* xp1 = x + ((size_t)(b0 + 1) * T_SEQ + t0) * IN_DIM;
            float v0 = bs0, v1 = bs0;
            #pragma unroll
            for (int k = 0; k < 20; ++k) {
                v0 = fmaf(wt[k], xp0[k], v0);
                v1 = fmaf(wt[k], xp1[k], v1);
            }
            xbuf[t0 * 50 + lane] = (f2){v0, v1};
        }
    }
    __syncthreads();

    for (int s = 0; s < T_SEQ + 3; ++s) {
        const int p = s & 1, pm = p ^ 1, q3 = s % 3;

        // ================= phase A =================
        if (w < 6) {
            if (lane < 50 && s >= l && s - l < T_SEQ) {
                const f2 *vA, *vB;
                if (l == 0)      { vA = xbuf  + q3 * 50; vB = h1buf + pm * 50; }
                else if (l == 1) { vA = h1buf + pm * 50; vB = h2buf + p  * 50; }
                else             { vA = h2buf + p  * 50; vB = h3buf + pm * 50; }
                const float4* v4 = (const float4*)(kside ? vB : vA);

                float ax[4], ay[4];
                ax[0] = bs0; ax[1] = bs1; ax[2] = bs2; ax[3] = bs3;
                ay[0] = bs0; ay[1] = bs1; ay[2] = bs2; ay[3] = bs3;
                #pragma unroll
                for (int k2 = 0; k2 < 25; ++k2) {     // 25 b128 per lane (half-K)
                    float4 q = v4[k2];
                    #pragma unroll
                    for (int g = 0; g < 4; ++g) {
                        ax[g] = fmaf(wt[g * 50 + 2 * k2],     q.x, ax[g]);
                        ay[g] = fmaf(wt[g * 50 + 2 * k2],     q.y, ay[g]);
                        ax[g] = fmaf(wt[g * 50 + 2 * k2 + 1], q.z, ax[g]);
                        ay[g] = fmaf(wt[g * 50 + 2 * k2 + 1], q.w, ay[g]);
                    }
                }
                // butterfly merge: both lanes of the pair get the full sums
                float fx[4], fy[4];
                #pragma unroll
                for (int g = 0; g < 4; ++g) {
                    fx[g] = ax[g] + swz1(ax[g]);
                    fy[g] = ay[g] + swz1(ay[g]);
                }
                float iix = sigm(fx[0]),   iiy = sigm(fy[0]);
                float ffx = sigm(fx[1]),   ffy = sigm(fy[1]);
                float ggx = tanh_f(fx[2]), ggy = tanh_f(fy[2]);
                float oox = sigm(fx[3]),   ooy = sigm(fy[3]);

                if (l == 0) {                          // L1 combine in-lane
                    c1x = fmaf(ffx, c1x, iix * ggx);
                    c1y = fmaf(ffy, c1y, iiy * ggy);
                    if (!kside)
                        h1buf[p * 50 + u] = (f2){oox * tanh_f(c1x), ooy * tanh_f(c1y)};
                } else if (l == 2) {                   // L3 combine (c3 == 0)
                    float cx = iix * ggx, cy = iiy * ggy;
                    if (!kside) {
                        h3buf[p * 50 + u] = (f2){oox * tanh_f(cx), ooy * tanh_f(cy)};
                        cn3buf[u] = (f2){cx, cy};
                    }
                } else {                               // L2: save for phase B
                    sg[0] = iix; sg[1] = iiy; sg[2] = ffx; sg[3] = ffy;
                    sg[4] = ggx; sg[5] = ggy; sg[6] = oox; sg[7] = ooy;
                }
            }
        } else if (w == 6) {                           // linear1, t = s+2
            if (lane < 50 && s + 2 < T_SEQ) {
                const int t = s + 2;
                const float* xp0 = x + ((size_t)b0 * T_SEQ + t) * IN_DIM;
                const float* xp1 = x + ((size_t)(b0 + 1) * T_SEQ + t) * IN_DIM;
                float v0 = bs0, v1 = bs0;
                #pragma unroll
                for (int k = 0; k < 20; ++k) {
                    v0 = fmaf(wt[k], xp0[k], v0);
                    v1 = fmaf(wt[k], xp1[k], v1);
                }
                xbuf[(t % 3) * 50 + lane] = (f2){v0, v1};
            }
        } else {                                       // out-proj, t = s-3
            if (lane < 8 && s >= 3 && s - 3 < T_SEQ) {
                const int t = s - 3;
                const float4* h4 = (const float4*)(h3buf + pm * 50);
                float a0 = bs0, a1 = bs0;
                #pragma unroll
                for (int k2 = 0; k2 < 25; ++k2) {
                    float4 q = h4[k2];
                    a0 = fmaf(wt[2 * k2],     q.x, a0);
                    a1 = fmaf(wt[2 * k2],     q.y, a1);
                    a0 = fmaf(wt[2 * k2 + 1], q.z, a0);
                    a1 = fmaf(wt[2 * k2 + 1], q.w, a1);
                }
                out[((size_t)b0 * T_SEQ + t) * OUT_DIM + lane]       = a0;
                out[((size_t)(b0 + 1) * T_SEQ + t) * OUT_DIM + lane] = a1;
            }
        }
        __syncthreads();

        // ================= phase B: L2 combine (needs cn3 from this step) ====
        if (w < 6 && l == 1 && lane < 50 && s >= 1 && s <= T_SEQ) {
            f2 cn3 = cn3buf[u];
            float c2x = fmaf(sg[2], cn3.x, sg[0] * sg[4]);
            float c2y = fmaf(sg[3], cn3.y, sg[1] * sg[5]);
            if (!kside)
                h2buf[pm * 50 + u] = (f2){sg[6] * tanh_f(c2x), sg[7] * tanh_f(c2y)};
        }
        __syncthreads();
    }
}

extern "C" void kernel_launch(void* const* d_in, const int* in_sizes, int n_in,
                              void* d_out, int out_size, void* d_ws, size_t ws_size,
                              hipStream_t stream) {
    const float* x    = (const float*)d_in[0];
    const float* W1   = (const float*)d_in[1];
    const float* b1   = (const float*)d_in[2];
    const float* Wih1 = (const float*)d_in[3];
    const float* Whh1 = (const float*)d_in[4];
    const float* bih1 = (const float*)d_in[5];
    const float* bhh1 = (const float*)d_in[6];
    const float* Wih2 = (const float*)d_in[7];
    const float* Whh2 = (const float*)d_in[8];
    const float* bih2 = (const float*)d_in[9];
    const float* bhh2 = (const float*)d_in[10];
    const float* Wih3 = (const float*)d_in[11];
    const float* Whh3 = (const float*)d_in[12];
    const float* bih3 = (const float*)d_in[13];
    const float* bhh3 = (const float*)d_in[14];
    const float* W2   = (const float*)d_in[15];
    const float* b2   = (const float*)d_in[16];
    float* out = (float*)d_out;

    dim3 grid(256), block(512);   // 8 waves: 6 gate + prefetch + out
    lstm_net_kernel<<<grid, block, 0, stream>>>(
        x, W1, b1, Wih1, Whh1, bih1, bhh1, Wih2, Whh2, bih2, bhh2,
        Wih3, Whh3, bih3, bhh3, W2, b2, out);
}

// Round 6
// 2293.983 us; speedup vs baseline: 5.9765x; 1.1589x over previous
//
#include <hip/hip_runtime.h>

// LSTM net: linear1(20->50) -> 3x LSTMCell(50, buggy c-flow) -> linear2(50->8)
// B=512, T=1024.  256 blocks x 512 threads (8 waves), 2 batch (f2) per block.
//
// R6: rebalanced 2-phase pipeline. Phase A runs ALL layer dot products at
// skew L1:t=s, L2:t=s-1, L3:t=s-2 (plus out t=s-3 and linear1 prefetch
// t=s+1). Phase B is only the L2-combine: L2's activated gates persist
// IN-REGISTER across the barrier; cn3 (L3's cell, the buggy c2 input) is
// handed through LDS from phase A. vs R5: no gbuf round-trip for L1/L3
// (combine in-lane), L2 dots moved off the critical phase-B path, all 8
// waves busy in phase A (SIMD balance), 2 barriers/step retained (the
// L2<->L3 one-step cycle requires intra-step ordering).
//
// Wave roles: w0,w1=L1  w2,w3=L3  w4,w5=L2 (dots A / combine B)
//             w6=linear1 prefetch  w7=out-projection
// Gate-wave lanes: u=(w&1)*25+(lane>>1), kside=lane&1 (0:Wih*vA, 1:Whh*vB),
// 4 gates/lane (200 wt), ds_swizzle xor-1 butterfly merges the K-halves.

#define T_SEQ  1024
#define IN_DIM 20
#define OUT_DIM 8

typedef float f2 __attribute__((ext_vector_type(2)));

__device__ __forceinline__ float swz1(float v) {   // lane ^= 1 butterfly
    return __int_as_float(__builtin_amdgcn_ds_swizzle(__float_as_int(v), 0x041F));
}
__device__ __forceinline__ float sigm(float x) {
    return __builtin_amdgcn_rcpf(1.0f + __expf(-x));
}
__device__ __forceinline__ float tanh_f(float x) {
    return fmaf(2.0f, sigm(2.0f * x), -1.0f);
}

__global__ __launch_bounds__(512, 2) void lstm_net_kernel(
    const float* __restrict__ x,
    const float* __restrict__ W1,   const float* __restrict__ b1,
    const float* __restrict__ Wih1, const float* __restrict__ Whh1,
    const float* __restrict__ bih1, const float* __restrict__ bhh1,
    const float* __restrict__ Wih2, const float* __restrict__ Whh2,
    const float* __restrict__ bih2, const float* __restrict__ bhh2,
    const float* __restrict__ Wih3, const float* __restrict__ Whh3,
    const float* __restrict__ bih3, const float* __restrict__ bhh3,
    const float* __restrict__ W2,   const float* __restrict__ b2,
    float* __restrict__ out)
{
    __shared__ __align__(16) f2 smem[450];
    f2* xbuf   = smem;         // [2][50] slot t&1
    f2* h1buf  = smem + 100;   // [2][50] slot t&1
    f2* h2buf  = smem + 200;   // [2][50] slot t&1
    f2* h3buf  = smem + 300;   // [2][50] slot t&1
    f2* cn3buf = smem + 400;   // [50] single (A-write by L3, B-read by L2)

    const int tid  = threadIdx.x;
    const int w    = tid >> 6;
    const int lane = tid & 63;
    const int b0   = blockIdx.x * 2;

    for (int i = tid; i < 450; i += 512) smem[i] = (f2){0.f, 0.f};

    // gate-wave geometry (w0..w5)
    const int l     = (w < 2) ? 0 : (w < 4) ? 2 : 1;   // w0,1:L1  w2,3:L3  w4,5:L2
    const int kside = lane & 1;
    const int u     = (w & 1) * 25 + (lane >> 1);

    float wt[200];
    float bs0 = 0.f, bs1 = 0.f, bs2 = 0.f, bs3 = 0.f;
    float c1x = 0.f, c1y = 0.f;            // L1 cell (w0,w1)
    float cn3x = 0.f, cn3y = 0.f;          // scratch
    float sg[8];                           // L2 activated gates (A->B carry)

    if (w < 6) {
        if (lane < 50) {
            const float* Wsrc; const float* bi; const float* bh;
            if (l == 0)      { Wsrc = kside ? Whh1 : Wih1; bi = bih1; bh = bhh1; }
            else if (l == 1) { Wsrc = kside ? Whh2 : Wih2; bi = bih2; bh = bhh2; }
            else             { Wsrc = kside ? Whh3 : Wih3; bi = bih3; bh = bhh3; }
            #pragma unroll
            for (int g = 0; g < 4; ++g)
                #pragma unroll
                for (int k = 0; k < 50; ++k)
                    wt[g * 50 + k] = Wsrc[(g * 50 + u) * 50 + k];
            if (!kside) {
                bs0 = bi[u]       + bh[u];
                bs1 = bi[50 + u]  + bh[50 + u];
                bs2 = bi[100 + u] + bh[100 + u];
                bs3 = bi[150 + u] + bh[150 + u];
            }
        }
    } else if (w == 6) {
        if (lane < 50) {
            #pragma unroll
            for (int k = 0; k < 20; ++k) wt[k] = W1[lane * 20 + k];
            bs0 = b1[lane];
        }
    } else {
        if (lane < 16) {
            const int ok = lane & 7;
            #pragma unroll
            for (int k = 0; k < 50; ++k) wt[k] = W2[ok * 50 + k];
            bs0 = b2[ok];
        }
    }
    __syncthreads();

    if (w == 6 && lane < 50) {              // prologue: x~(0) -> xbuf[0]
        const float* xp0 = x + (size_t)b0 * T_SEQ * IN_DIM;
        const float* xp1 = x + (size_t)(b0 + 1) * T_SEQ * IN_DIM;
        float v0 = bs0, v1 = bs0;
        #pragma unroll
        for (int k = 0; k < 20; ++k) {
            v0 = fmaf(wt[k], xp0[k], v0);
            v1 = fmaf(wt[k], xp1[k], v1);
        }
        xbuf[lane] = (f2){v0, v1};
    }
    __syncthreads();

    for (int s = 0; s <= T_SEQ + 2; ++s) {           // 1027 steps
        // ================= phase A =================
        if (w < 6) {
            // layer timestep: L1 t=s, L2 t=s-1, L3 t=s-2
            const int tl = s - ((l == 0) ? 0 : (l == 1) ? 1 : 2);
            if (lane < 50 && tl >= 0 && tl < T_SEQ) {
                const f2 *vA, *vB;
                if (l == 0)      { vA = xbuf  + (s & 1) * 50;       vB = h1buf + ((s - 1) & 1) * 50; }
                else if (l == 1) { vA = h1buf + ((s - 1) & 1) * 50; vB = h2buf + ((s - 2) & 1) * 50; }
                else             { vA = h2buf + ((s - 2) & 1) * 50; vB = h3buf + ((s - 3) & 1) * 50; }
                const float4* v4 = (const float4*)(kside ? vB : vA);

                float ax[4], ay[4];
                ax[0] = bs0; ax[1] = bs1; ax[2] = bs2; ax[3] = bs3;
                ay[0] = bs0; ay[1] = bs1; ay[2] = bs2; ay[3] = bs3;
                #pragma unroll
                for (int k2 = 0; k2 < 25; ++k2) {
                    float4 q = v4[k2];
                    #pragma unroll
                    for (int g = 0; g < 4; ++g) {
                        ax[g] = fmaf(wt[g * 50 + 2 * k2],     q.x, ax[g]);
                        ay[g] = fmaf(wt[g * 50 + 2 * k2],     q.y, ay[g]);
                        ax[g] = fmaf(wt[g * 50 + 2 * k2 + 1], q.z, ax[g]);
                        ay[g] = fmaf(wt[g * 50 + 2 * k2 + 1], q.w, ay[g]);
                    }
                }
                float fx[4], fy[4];
                #pragma unroll
                for (int g = 0; g < 4; ++g) {
                    fx[g] = ax[g] + swz1(ax[g]);
                    fy[g] = ay[g] + swz1(ay[g]);
                }
                float iix = sigm(fx[0]),   iiy = sigm(fy[0]);
                float ffx = sigm(fx[1]),   ffy = sigm(fy[1]);
                float ggx = tanh_f(fx[2]), ggy = tanh_f(fy[2]);
                float oox = sigm(fx[3]),   ooy = sigm(fy[3]);

                if (l == 0) {                          // L1 combine in-lane
                    c1x = fmaf(ffx, c1x, iix * ggx);
                    c1y = fmaf(ffy, c1y, iiy * ggy);
                    if (!kside)
                        h1buf[(s & 1) * 50 + u] = (f2){oox * tanh_f(c1x), ooy * tanh_f(c1y)};
                } else if (l == 2) {                   // L3 combine (c3==0)
                    cn3x = iix * ggx; cn3y = iiy * ggy;
                    if (!kside) {
                        h3buf[((s - 2) & 1) * 50 + u] =
                            (f2){oox * tanh_f(cn3x), ooy * tanh_f(cn3y)};
                        cn3buf[u] = (f2){cn3x, cn3y};
                    }
                } else {                               // L2: carry gates to B
                    sg[0] = iix; sg[1] = iiy; sg[2] = ffx; sg[3] = ffy;
                    sg[4] = ggx; sg[5] = ggy; sg[6] = oox; sg[7] = ooy;
                }
            }
        } else if (w == 6) {                           // linear1, t = s+1
            if (lane < 50 && s + 1 < T_SEQ) {
                const int t = s + 1;
                const float* xp0 = x + ((size_t)b0 * T_SEQ + t) * IN_DIM;
                const float* xp1 = x + ((size_t)(b0 + 1) * T_SEQ + t) * IN_DIM;
                float v0 = bs0, v1 = bs0;
                #pragma unroll
                for (int k = 0; k < 20; ++k) {
                    v0 = fmaf(wt[k], xp0[k], v0);
                    v1 = fmaf(wt[k], xp1[k], v1);
                }
                xbuf[(t & 1) * 50 + lane] = (f2){v0, v1};
            }
        } else {                                       // out-proj, t = s-3
            if (lane < 16 && s >= 3 && s - 3 < T_SEQ) {
                const int t  = s - 3;
                const int ob = lane >> 3;              // batch sel
                const int ok = lane & 7;
                const float4* h4 = (const float4*)(h3buf + ((s - 3) & 1) * 50);
                float acc = bs0;
                #pragma unroll
                for (int k2 = 0; k2 < 25; ++k2) {
                    float4 q = h4[k2];
                    float e0 = ob ? q.y : q.x;
                    float e1 = ob ? q.w : q.z;
                    acc = fmaf(wt[2 * k2],     e0, acc);
                    acc = fmaf(wt[2 * k2 + 1], e1, acc);
                }
                out[((size_t)(b0 + ob) * T_SEQ + t) * OUT_DIM + ok] = acc;
            }
        }
        __syncthreads();

        // ================= phase B: L2 combine only =================
        if ((w == 4 || w == 5) && lane < 50 && !kside && s >= 1 && s <= T_SEQ) {
            f2 cn3 = cn3buf[u];                        // c2 <- L3 cell (bug)
            float c2x = fmaf(sg[2], cn3.x, sg[0] * sg[4]);
            float c2y = fmaf(sg[3], cn3.y, sg[1] * sg[5]);
            h2buf[((s - 1) & 1) * 50 + u] =
                (f2){sg[6] * tanh_f(c2x), sg[7] * tanh_f(c2y)};
        }
        __syncthreads();
    }
}

extern "C" void kernel_launch(void* const* d_in, const int* in_sizes, int n_in,
                              void* d_out, int out_size, void* d_ws, size_t ws_size,
                              hipStream_t stream) {
    const float* x    = (const float*)d_in[0];
    const float* W1   = (const float*)d_in[1];
    const float* b1   = (const float*)d_in[2];
    const float* Wih1 = (const float*)d_in[3];
    const float* Whh1 = (const float*)d_in[4];
    const float* bih1 = (const float*)d_in[5];
    const float* bhh1 = (const float*)d_in[6];
    const float* Wih2 = (const float*)d_in[7];
    const float* Whh2 = (const float*)d_in[8];
    const float* bih2 = (const float*)d_in[9];
    const float* bhh2 = (const float*)d_in[10];
    const float* Wih3 = (const float*)d_in[11];
    const float* Whh3 = (const float*)d_in[12];
    const float* bih3 = (const float*)d_in[13];
    const float* bhh3 = (const float*)d_in[14];
    const float* W2   = (const float*)d_in[15];
    const float* b2   = (const float*)d_in[16];
    float* out = (float*)d_out;

    dim3 grid(256), block(512);   // 8 waves: 6 gate + prefetch + out
    lstm_net_kernel<<<grid, block, 0, stream>>>(
        x, W1, b1, Wih1, Whh1, bih1, bhh1, Wih2, Whh2, bih2, bhh2,
        Wih3, Whh3, bih3, bhh3, W2, b2, out);
}